// Round 5
// baseline (130.879 us; speedup 1.0000x reference)
//
#include <hip/hip_runtime.h>
#include <math.h>

#define D    128
#define CCLS 64
#define SLP  68   // padded LDS row stride (floats): 16B-aligned, 2-way banks max

typedef _Float16 f16x8 __attribute__((ext_vector_type(8)));
typedef _Float16 f16x4 __attribute__((ext_vector_type(4)));
typedef float    f32x4 __attribute__((ext_vector_type(4)));

__device__ __forceinline__ float wave_reduce_sum(float v) {
    #pragma unroll
    for (int off = 32; off > 0; off >>= 1) v += __shfl_xor(v, off, 64);
    return v;
}

// --- class histogram: ONE block, LDS atomics only ---------------------------
__global__ void hist_kernel(const int* __restrict__ t2, const int* __restrict__ t3,
                            float* __restrict__ cls_freq, int N, int M) {
    __shared__ int h[CCLS];
    int t = threadIdx.x;
    if (t < CCLS) h[t] = 0;
    __syncthreads();
    for (int i = t; i < M; i += blockDim.x) {
        int lab = (i < N) ? t2[i] : t3[i - N];
        atomicAdd(&h[lab], 1);
    }
    __syncthreads();
    if (t < CCLS) cls_freq[t] = (float)h[t] + 1.0f + 1e-6f;
}

// --- normalize rows (feats ++ protos ++ zero-pad), fold sqrt(log2e/TAU),
//     cast f16, MFMA-tiled layout: elem(r,k) ->
//     ((r>>4)*16 + (k>>3))*128 + (r&15)*8 + (k&7).  One wave per row.
//     ALSO: first 2048 waves build the one-hot table in 16x16x16 B-frag
//     layout: tile(jt,ct)=512B, lane holds oh[jt*16+4g+e][ct*16+li], e=0..3.
__global__ void norm_kernel(const float* __restrict__ protos,
                            const float* __restrict__ proj2,
                            const float* __restrict__ proj3,
                            const int* __restrict__ t2, const int* __restrict__ t3,
                            _Float16* __restrict__ ftile,
                            _Float16* __restrict__ oh, int N, int M) {
    const float SCL = 3.8017368953f;  // sqrt(10 * log2(e))
    int w = threadIdx.x >> 6;
    int lane = threadIdx.x & 63;
    int g = lane >> 4, li = lane & 15;
    int row = blockIdx.x * (blockDim.x >> 6) + w;
    const int MT = M + 128;

    if (row < MT) {
        const float* src = nullptr;
        if (row < M)             src = (row < N) ? proj2 + (size_t)row * D
                                                 : proj3 + (size_t)(row - N) * D;
        else if (row < M + CCLS) src = protos + (size_t)(row - M) * D;
        float2 v = {0.f, 0.f};
        if (src) v = ((const float2*)src)[lane];
        float ss = wave_reduce_sum(v.x * v.x + v.y * v.y);
        float scale = src ? SCL / fmaxf(sqrtf(ss), 1e-12f) : 0.f;
        _Float16 h0 = (_Float16)(v.x * scale), h1 = (_Float16)(v.y * scale);
        int k0 = 2 * lane;
        size_t off = ((size_t)(row >> 4) * 16 + (k0 >> 3)) * 128 + (row & 15) * 8 + (k0 & 7);
        ftile[off] = h0; ftile[off + 1] = h1;
    }

    int wid = blockIdx.x * (blockDim.x >> 6) + w;
    if (wid < (M / 16) * 4) {
        int jt = wid >> 2, ct = wid & 3;
        int c = ct * 16 + li;
        f16x4 v;
        #pragma unroll
        for (int e = 0; e < 4; ++e) {
            int j = jt * 16 + 4 * g + e;
            int labj = (j < N) ? t2[j] : t3[j - N];
            v[e] = (labj == c) ? (_Float16)1.0f : (_Float16)0.0f;
        }
        *(f16x4*)(oh + ((size_t)(jt * 4 + ct)) * 256 + lane * 4) = v;
    }
}

// --- main: 64-row panel per block.x, j-chunk per block.y. Each wave owns 8
//     col-slices. Stage1: mfma_16x16x32_f16 (swapped) -> sim tile. exp2 ->
//     cvt_pkrtz -> stage2 A-frag. Stage2: S[i][c] += P * onehot on the MFMA
//     pipe. Cross-wave reduce in LDS (ds_add_f32), per-chunk partial written
//     with plain float4 stores (NO global atomics).
__global__ __launch_bounds__(256, 2)
void sim_kernel(const _Float16* __restrict__ ftile,
                const _Float16* __restrict__ oh,
                float* __restrict__ Spart, float* __restrict__ E, int M) {
    __shared__ float Sl[64][SLP];

    const int panel = blockIdx.x;           // [0, M/64)
    const int chunk = blockIdx.y;           // [0, 4)
    const int t = threadIdx.x;
    const int w = t >> 6, lane = t & 63;
    const int g = lane >> 4, li = lane & 15;
    const int lo = g * 128 + li * 8;
    const int W = chunk * 4 + w;            // [0,16)
    const int rowBase = panel * 64;
    const int rtA = panel * 4;
    const int nSlices = M / 64;             // 128

    for (int i = t; i < 64 * SLP; i += 256) ((float*)Sl)[i] = 0.f;

    // hoisted A fragments: panel's 64 rows x 128 k
    f16x8 a[4][4];
    #pragma unroll
    for (int m = 0; m < 4; ++m)
        #pragma unroll
        for (int kt = 0; kt < 4; ++kt)
            a[m][kt] = *(const f16x8*)(ftile + (size_t)(rtA + m) * 2048 + kt * 512 + lo);

    f32x4 acc2[4][4];                       // acc2[m][nc]: i=16m+4g+r, c=16nc+li
    #pragma unroll
    for (int m = 0; m < 4; ++m)
        #pragma unroll
        for (int nc = 0; nc < 4; ++nc)
            #pragma unroll
            for (int r = 0; r < 4; ++r) acc2[m][nc][r] = 0.f;

    const int s0 = W * (nSlices / 16);
    for (int si = 0; si <= 8; ++si) {
        bool isProto = (si == 8);
        if (isProto && W != 0) break;
        const int rb0 = isProto ? (M / 16) : (s0 + si) * 4;
        const int s = s0 + si;

        f32x4 acc[4][4];
        #pragma unroll
        for (int m = 0; m < 4; ++m)
            #pragma unroll
            for (int n = 0; n < 4; ++n)
                #pragma unroll
                for (int r = 0; r < 4; ++r) acc[m][n][r] = 0.f;

        #pragma unroll
        for (int kt = 0; kt < 4; ++kt) {
            f16x8 b[4];
            #pragma unroll
            for (int n = 0; n < 4; ++n)
                b[n] = *(const f16x8*)(ftile + (size_t)(rb0 + n) * 2048 + kt * 512 + lo);
            #pragma unroll
            for (int m = 0; m < 4; ++m)
                #pragma unroll
                for (int n = 0; n < 4; ++n)
                    acc[m][n] = __builtin_amdgcn_mfma_f32_16x16x32_f16(b[n], a[m][kt], acc[m][n], 0, 0, 0);
        }

        if (isProto) {
            #pragma unroll
            for (int m = 0; m < 4; ++m)
                #pragma unroll
                for (int n = 0; n < 4; ++n)
                    #pragma unroll
                    for (int r = 0; r < 4; ++r) {
                        float e = exp2f(acc[m][n][r]);
                        E[(size_t)(rowBase + m * 16 + li) * 64 + n * 16 + 4 * g + r] = e;
                    }
            continue;
        }

        if (s == panel) {   // diagonal slice: mask e_ii -> 0
            #pragma unroll
            for (int m = 0; m < 4; ++m)
                #pragma unroll
                for (int r = 0; r < 4; ++r)
                    acc[m][m][r] = (4 * g + r == li) ? -1e4f : acc[m][m][r];
        }

        #pragma unroll
        for (int n = 0; n < 4; ++n) {
            f16x4 pa[4];
            #pragma unroll
            for (int m = 0; m < 4; ++m) {
                auto l2 = __builtin_amdgcn_cvt_pkrtz(exp2f(acc[m][n][0]), exp2f(acc[m][n][1]));
                auto h2 = __builtin_amdgcn_cvt_pkrtz(exp2f(acc[m][n][2]), exp2f(acc[m][n][3]));
                f16x4 p; p.x = l2.x; p.y = l2.y; p.z = h2.x; p.w = h2.y;
                pa[m] = p;
            }
            #pragma unroll
            for (int nc = 0; nc < 4; ++nc) {
                f16x4 ohf = *(const f16x4*)(oh + ((size_t)(s * 4 + n) * 4 + nc) * 256 + lane * 4);
                #pragma unroll
                for (int m = 0; m < 4; ++m)
                    acc2[m][nc] = __builtin_amdgcn_mfma_f32_16x16x16f16(pa[m], ohf, acc2[m][nc], 0, 0, 0);
            }
        }
    }

    // cross-wave reduce via LDS float atomics (2-way bank conflicts max)
    __syncthreads();
    #pragma unroll
    for (int m = 0; m < 4; ++m)
        #pragma unroll
        for (int nc = 0; nc < 4; ++nc)
            #pragma unroll
            for (int r = 0; r < 4; ++r)
                atomicAdd(&Sl[m * 16 + 4 * g + r][nc * 16 + li], acc2[m][nc][r]);
    __syncthreads();

    // plain-store this chunk's 64x64 partial
    float* dst = Spart + ((size_t)chunk * (M / 64) + panel) * 4096;
    {
        const int row = t >> 2, cb = (t & 3) * 16;
        #pragma unroll
        for (int k4 = 0; k4 < 4; ++k4) {
            f32x4 v = *(const f32x4*)&Sl[row][cb + 4 * k4];
            *(f32x4*)(dst + (size_t)row * 64 + cb + 4 * k4) = v;
        }
    }
}

// --- per-row loss: one wave per row, lane = class ---------------------------
__global__ void fin_kernel(const int* __restrict__ t2, const int* __restrict__ t3,
                           const float* __restrict__ cls_freq,
                           const float* __restrict__ Spart, const float* __restrict__ E,
                           float* __restrict__ loss, int N, int M) {
    int w = threadIdx.x >> 6, lane = threadIdx.x & 63;
    int i = blockIdx.x * (blockDim.x >> 6) + w;
    if (i >= M) return;
    const int panel = i >> 6, lrow = i & 63;
    const size_t pbase = (size_t)panel * 4096 + (size_t)lrow * 64 + lane;
    const size_t cstride = (size_t)(M / 64) * 4096;
    float s = Spart[pbase] + Spart[pbase + cstride]
            + Spart[pbase + 2 * cstride] + Spart[pbase + 3 * cstride];
    float ev = E[(size_t)i * 64 + lane];
    float fr = cls_freq[lane];
    float sumS  = wave_reduce_sum(s);
    float sumEw = wave_reduce_sum(ev / fr);
    int lab = (i < N) ? t2[i] : t3[i - N];
    float nmr = __shfl(s + ev, lab, 64);
    float fl  = __shfl(fr, lab, 64);
    float denom = sumS / fl + sumEw;
    if (lane == 0) loss[i] = logf(denom + 1e-12f) - logf(nmr);
}

// --- mean reduction: one block -----------------------------------------------
__global__ void out_kernel(const float* __restrict__ loss, float* __restrict__ out, int M) {
    float s = 0.f;
    for (int i = threadIdx.x; i < M; i += 1024) s += loss[i];
    s = wave_reduce_sum(s);
    __shared__ float ws_[16];
    if ((threadIdx.x & 63) == 0) ws_[threadIdx.x >> 6] = s;
    __syncthreads();
    if (threadIdx.x == 0) {
        float t = 0.f;
        for (int k = 0; k < 16; ++k) t += ws_[k];
        out[0] = t / (float)M;
    }
}

extern "C" void kernel_launch(void* const* d_in, const int* in_sizes, int n_in,
                              void* d_out, int out_size, void* d_ws, size_t ws_size,
                              hipStream_t stream) {
    const float* protos = (const float*)d_in[0];
    const float* proj2  = (const float*)d_in[1];
    const int*   t2     = (const int*)d_in[2];
    const float* proj3  = (const float*)d_in[3];
    const int*   t3     = (const int*)d_in[4];
    float* out = (float*)d_out;

    const int N = in_sizes[1] / D;   // 4096
    const int M = 2 * N;             // 8192
    const int MT = M + 128;

    _Float16* ftile = (_Float16*)d_ws;                          // MT*D halfs
    _Float16* oh    = ftile + (size_t)MT * D;                   // (M/16)*4*256 halfs
    float* Spart    = (float*)(oh + (size_t)(M / 16) * 4 * 256); // 4*(M/64)*4096
    float* E        = Spart + (size_t)4 * (M / 64) * 4096;      // M*64
    float* loss     = E + (size_t)M * 64;                       // M
    float* cls_freq = loss + M;                                 // 64

    hist_kernel<<<1, 1024, 0, stream>>>(t2, t3, cls_freq, N, M);
    norm_kernel<<<(MT + 3) / 4, 256, 0, stream>>>(protos, proj2, proj3, t2, t3,
                                                  ftile, oh, N, M);
    dim3 grid(M / 64, 4);
    sim_kernel<<<grid, 256, 0, stream>>>(ftile, oh, Spart, E, M);
    fin_kernel<<<(M + 3) / 4, 256, 0, stream>>>(t2, t3, cls_freq, Spart, E, loss, N, M);
    out_kernel<<<1, 1024, 0, stream>>>(loss, out, M);
}

// Round 6
// 126.130 us; speedup vs baseline: 1.0376x; 1.0376x over previous
//
#include <hip/hip_runtime.h>
#include <math.h>

#define D    128
#define CCLS 64
#define SLP  68   // padded LDS row stride (floats)

typedef _Float16 f16x8 __attribute__((ext_vector_type(8)));
typedef _Float16 f16x4 __attribute__((ext_vector_type(4)));
typedef float    f32x4 __attribute__((ext_vector_type(4)));

__device__ __forceinline__ float wave_reduce_sum(float v) {
    #pragma unroll
    for (int off = 32; off > 0; off >>= 1) v += __shfl_xor(v, off, 64);
    return v;
}

// --- class histogram: ONE block, LDS atomics only ---------------------------
__global__ void hist_kernel(const int* __restrict__ t2, const int* __restrict__ t3,
                            float* __restrict__ cls_freq, int N, int M) {
    __shared__ int h[CCLS];
    int t = threadIdx.x;
    if (t < CCLS) h[t] = 0;
    __syncthreads();
    for (int i = t; i < M; i += blockDim.x) {
        int lab = (i < N) ? t2[i] : t3[i - N];
        atomicAdd(&h[lab], 1);
    }
    __syncthreads();
    if (t < CCLS) cls_freq[t] = (float)h[t] + 1.0f + 1e-6f;
}

// --- normalize rows (feats ++ protos ++ zero-pad), fold sqrt(log2e/TAU),
//     cast f16, MFMA-tiled layout: elem(r,k) ->
//     ((r>>4)*16 + (k>>3))*128 + (r&15)*8 + (k&7).  One wave per row.
//     ALSO: first 2048 waves build one-hot tiles in 16x16x16 B-frag layout.
__global__ void norm_kernel(const float* __restrict__ protos,
                            const float* __restrict__ proj2,
                            const float* __restrict__ proj3,
                            const int* __restrict__ t2, const int* __restrict__ t3,
                            _Float16* __restrict__ ftile,
                            _Float16* __restrict__ oh, int N, int M) {
    const float SCL = 3.8017368953f;  // sqrt(10 * log2(e))
    int w = threadIdx.x >> 6;
    int lane = threadIdx.x & 63;
    int g = lane >> 4, li = lane & 15;
    int row = blockIdx.x * (blockDim.x >> 6) + w;
    const int MT = M + 128;

    if (row < MT) {
        const float* src = nullptr;
        if (row < M)             src = (row < N) ? proj2 + (size_t)row * D
                                                 : proj3 + (size_t)(row - N) * D;
        else if (row < M + CCLS) src = protos + (size_t)(row - M) * D;
        float2 v = {0.f, 0.f};
        if (src) v = ((const float2*)src)[lane];
        float ss = wave_reduce_sum(v.x * v.x + v.y * v.y);
        float scale = src ? SCL / fmaxf(sqrtf(ss), 1e-12f) : 0.f;
        _Float16 h0 = (_Float16)(v.x * scale), h1 = (_Float16)(v.y * scale);
        int k0 = 2 * lane;
        size_t off = ((size_t)(row >> 4) * 16 + (k0 >> 3)) * 128 + (row & 15) * 8 + (k0 & 7);
        ftile[off] = h0; ftile[off + 1] = h1;
    }

    int wid = blockIdx.x * (blockDim.x >> 6) + w;
    if (wid < (M / 16) * 4) {
        int jt = wid >> 2, ct = wid & 3;
        int c = ct * 16 + li;
        f16x4 v;
        #pragma unroll
        for (int e = 0; e < 4; ++e) {
            int j = jt * 16 + 4 * g + e;
            int labj = (j < N) ? t2[j] : t3[j - N];
            v[e] = (labj == c) ? (_Float16)1.0f : (_Float16)0.0f;
        }
        *(f16x4*)(oh + ((size_t)(jt * 4 + ct)) * 256 + lane * 4) = v;
    }
}

// --- main: panel (64 rows) x chunk (32 slices) per block. 4 waves:
//     wave = (row-half ro, slice-half). Per wave: 32 rows, 16 slices.
//     Stage1: mfma_16x16x32_f16 (swapped) -> P tile (i=li, j=16n+4g+r).
//     exp2 -> cvt_pkrtz -> stage2 A-frag. Stage2: S[i][c] += P*onehot on
//     the MFMA pipe (acc2[2][4], i=ro+16m+4g+r, c=16nc+li).
//     Pair-reduce (half0 -> LDS, half1 adds) -> plain-store chunk partial.
//     Per-thread state halved vs R5 to eliminate scratch spill.
__global__ __launch_bounds__(256, 2)
void sim_kernel(const _Float16* __restrict__ ftile,
                const _Float16* __restrict__ oh,
                float* __restrict__ Spart, float* __restrict__ E, int M) {
    __shared__ float Sl[64][SLP];

    const int panel = blockIdx.x;           // [0, M/64)
    const int chunk = blockIdx.y;           // [0, 4)
    const int t = threadIdx.x;
    const int w = t >> 6, lane = t & 63;
    const int g = lane >> 4, li = lane & 15;
    const int lo = g * 128 + li * 8;
    const int ro = (w & 1) * 32;            // row offset within panel
    const int half = w >> 1;                // slice half
    const int rtA = panel * 4 + (ro >> 4);

    // A fragments: this wave's 32 rows x 128 k (32 VGPRs)
    f16x8 a[2][4];
    #pragma unroll
    for (int m = 0; m < 2; ++m)
        #pragma unroll
        for (int kt = 0; kt < 4; ++kt)
            a[m][kt] = *(const f16x8*)(ftile + (size_t)(rtA + m) * 2048 + kt * 512 + lo);

    f32x4 acc2[2][4];                       // i = ro+16m+4g+r, c = 16nc+li
    #pragma unroll
    for (int m = 0; m < 2; ++m)
        #pragma unroll
        for (int nc = 0; nc < 4; ++nc)
            #pragma unroll
            for (int r = 0; r < 4; ++r) acc2[m][nc][r] = 0.f;

    const int sBase = chunk * 32 + half * 16;
    for (int si = 0; si < 16; ++si) {
        const int s = sBase + si;
        const int rb0 = s * 4;

        f32x4 acc1[2][4];
        #pragma unroll
        for (int m = 0; m < 2; ++m)
            #pragma unroll
            for (int n = 0; n < 4; ++n)
                #pragma unroll
                for (int r = 0; r < 4; ++r) acc1[m][n][r] = 0.f;

        #pragma unroll
        for (int kt = 0; kt < 4; ++kt) {
            f16x8 b[4];
            #pragma unroll
            for (int n = 0; n < 4; ++n)
                b[n] = *(const f16x8*)(ftile + (size_t)(rb0 + n) * 2048 + kt * 512 + lo);
            #pragma unroll
            for (int m = 0; m < 2; ++m)
                #pragma unroll
                for (int n = 0; n < 4; ++n)
                    acc1[m][n] = __builtin_amdgcn_mfma_f32_16x16x32_f16(b[n], a[m][kt], acc1[m][n], 0, 0, 0);
        }

        if (s == panel) {   // diagonal slice: mask e_ii -> 0
            #pragma unroll
            for (int m = 0; m < 2; ++m) {
                const int nd = (ro >> 4) + m;
                #pragma unroll
                for (int r = 0; r < 4; ++r)
                    if (4 * g + r == li) acc1[m][nd][r] = -1e5f;
            }
        }

        #pragma unroll
        for (int n = 0; n < 4; ++n) {
            f16x4 pa[2];
            #pragma unroll
            for (int m = 0; m < 2; ++m) {
                auto l2 = __builtin_amdgcn_cvt_pkrtz(exp2f(acc1[m][n][0]), exp2f(acc1[m][n][1]));
                auto h2 = __builtin_amdgcn_cvt_pkrtz(exp2f(acc1[m][n][2]), exp2f(acc1[m][n][3]));
                f16x4 p; p.x = l2.x; p.y = l2.y; p.z = h2.x; p.w = h2.y;
                pa[m] = p;
            }
            #pragma unroll
            for (int nc = 0; nc < 4; ++nc) {
                f16x4 ohf = *(const f16x4*)(oh + ((size_t)(s * 4 + n) * 4 + nc) * 256 + lane * 4);
                #pragma unroll
                for (int m = 0; m < 2; ++m)
                    acc2[m][nc] = __builtin_amdgcn_mfma_f32_16x16x16f16(pa[m], ohf, acc2[m][nc], 0, 0, 0);
            }
        }
    }

    // pair-reduce: half0 writes LDS; half1 adds and stores chunk partial
    if (half == 0) {
        #pragma unroll
        for (int m = 0; m < 2; ++m)
            #pragma unroll
            for (int nc = 0; nc < 4; ++nc)
                #pragma unroll
                for (int r = 0; r < 4; ++r)
                    Sl[ro + 16 * m + 4 * g + r][nc * 16 + li] = acc2[m][nc][r];
    }
    __syncthreads();
    if (half == 1) {
        float* dst = Spart + ((size_t)chunk * gridDim.x + panel) * 4096;
        #pragma unroll
        for (int m = 0; m < 2; ++m)
            #pragma unroll
            for (int nc = 0; nc < 4; ++nc)
                #pragma unroll
                for (int r = 0; r < 4; ++r) {
                    const int row = ro + 16 * m + 4 * g + r, c = nc * 16 + li;
                    dst[(size_t)row * 64 + c] = acc2[m][nc][r] + Sl[row][c];
                }
    }

    // proto slice: chunk 0, half 0 waves (both row halves), E[i][c] direct
    if (chunk == 0 && half == 0) {
        const int rbp = M >> 4;
        f32x4 accp[2][4];
        #pragma unroll
        for (int m = 0; m < 2; ++m)
            #pragma unroll
            for (int n = 0; n < 4; ++n)
                #pragma unroll
                for (int r = 0; r < 4; ++r) accp[m][n][r] = 0.f;
        #pragma unroll
        for (int kt = 0; kt < 4; ++kt) {
            f16x8 b[4];
            #pragma unroll
            for (int n = 0; n < 4; ++n)
                b[n] = *(const f16x8*)(ftile + (size_t)(rbp + n) * 2048 + kt * 512 + lo);
            #pragma unroll
            for (int m = 0; m < 2; ++m)
                #pragma unroll
                for (int n = 0; n < 4; ++n)
                    accp[m][n] = __builtin_amdgcn_mfma_f32_16x16x32_f16(b[n], a[m][kt], accp[m][n], 0, 0, 0);
        }
        #pragma unroll
        for (int m = 0; m < 2; ++m)
            #pragma unroll
            for (int n = 0; n < 4; ++n)
                #pragma unroll
                for (int r = 0; r < 4; ++r)
                    E[(size_t)(panel * 64 + ro + 16 * m + li) * 64 + n * 16 + 4 * g + r]
                        = exp2f(accp[m][n][r]);
    }
}

// --- per-row loss: one wave per row, lane = class ---------------------------
__global__ void fin_kernel(const int* __restrict__ t2, const int* __restrict__ t3,
                           const float* __restrict__ cls_freq,
                           const float* __restrict__ Spart, const float* __restrict__ E,
                           float* __restrict__ loss, int N, int M) {
    int w = threadIdx.x >> 6, lane = threadIdx.x & 63;
    int i = blockIdx.x * (blockDim.x >> 6) + w;
    if (i >= M) return;
    const int panel = i >> 6, lrow = i & 63;
    const size_t pbase = (size_t)panel * 4096 + (size_t)lrow * 64 + lane;
    const size_t cstride = (size_t)(M / 64) * 4096;
    float s = Spart[pbase] + Spart[pbase + cstride]
            + Spart[pbase + 2 * cstride] + Spart[pbase + 3 * cstride];
    float ev = E[(size_t)i * 64 + lane];
    float fr = cls_freq[lane];
    float sumS  = wave_reduce_sum(s);
    float sumEw = wave_reduce_sum(ev / fr);
    int lab = (i < N) ? t2[i] : t3[i - N];
    float nmr = __shfl(s + ev, lab, 64);
    float fl  = __shfl(fr, lab, 64);
    float denom = sumS / fl + sumEw;
    if (lane == 0) loss[i] = logf(denom + 1e-12f) - logf(nmr);
}

// --- mean reduction: one block -----------------------------------------------
__global__ void out_kernel(const float* __restrict__ loss, float* __restrict__ out, int M) {
    float s = 0.f;
    for (int i = threadIdx.x; i < M; i += 1024) s += loss[i];
    s = wave_reduce_sum(s);
    __shared__ float ws_[16];
    if ((threadIdx.x & 63) == 0) ws_[threadIdx.x >> 6] = s;
    __syncthreads();
    if (threadIdx.x == 0) {
        float t = 0.f;
        for (int k = 0; k < 16; ++k) t += ws_[k];
        out[0] = t / (float)M;
    }
}

extern "C" void kernel_launch(void* const* d_in, const int* in_sizes, int n_in,
                              void* d_out, int out_size, void* d_ws, size_t ws_size,
                              hipStream_t stream) {
    const float* protos = (const float*)d_in[0];
    const float* proj2  = (const float*)d_in[1];
    const int*   t2     = (const int*)d_in[2];
    const float* proj3  = (const float*)d_in[3];
    const int*   t3     = (const int*)d_in[4];
    float* out = (float*)d_out;

    const int N = in_sizes[1] / D;   // 4096
    const int M = 2 * N;             // 8192
    const int MT = M + 128;

    _Float16* ftile = (_Float16*)d_ws;                          // MT*D halfs
    _Float16* oh    = ftile + (size_t)MT * D;                   // (M/16)*4*256 halfs
    float* Spart    = (float*)(oh + (size_t)(M / 16) * 4 * 256); // 4*(M/64)*4096
    float* E        = Spart + (size_t)4 * (M / 64) * 4096;      // M*64
    float* loss     = E + (size_t)M * 64;                       // M
    float* cls_freq = loss + M;                                 // 64

    hist_kernel<<<1, 1024, 0, stream>>>(t2, t3, cls_freq, N, M);
    norm_kernel<<<(MT + 3) / 4, 256, 0, stream>>>(protos, proj2, proj3, t2, t3,
                                                  ftile, oh, N, M);
    dim3 grid(M / 64, 4);
    sim_kernel<<<grid, 256, 0, stream>>>(ftile, oh, Spart, E, M);
    fin_kernel<<<(M + 3) / 4, 256, 0, stream>>>(t2, t3, cls_freq, Spart, E, loss, N, M);
    out_kernel<<<1, 1024, 0, stream>>>(loss, out, M);
}

// Round 7
// 69.034 us; speedup vs baseline: 1.8959x; 1.8271x over previous
//
#include <hip/hip_runtime.h>
#include <math.h>

#define D    128
#define CCLS 64
#define SLP  68   // padded LDS row stride (floats)

typedef _Float16 f16x8 __attribute__((ext_vector_type(8)));
typedef _Float16 f16x4 __attribute__((ext_vector_type(4)));
typedef float    f32x4 __attribute__((ext_vector_type(4)));

__device__ __forceinline__ float wave_reduce_sum(float v) {
    #pragma unroll
    for (int off = 32; off > 0; off >>= 1) v += __shfl_xor(v, off, 64);
    return v;
}

// --- class histogram: ONE block, LDS atomics only ---------------------------
__global__ void hist_kernel(const int* __restrict__ t2, const int* __restrict__ t3,
                            float* __restrict__ cls_freq, int N, int M) {
    __shared__ int h[CCLS];
    int t = threadIdx.x;
    if (t < CCLS) h[t] = 0;
    __syncthreads();
    for (int i = t; i < M; i += blockDim.x) {
        int lab = (i < N) ? t2[i] : t3[i - N];
        atomicAdd(&h[lab], 1);
    }
    __syncthreads();
    if (t < CCLS) cls_freq[t] = (float)h[t] + 1.0f + 1e-6f;
}

// --- normalize rows (feats ++ protos ++ zero-pad), fold sqrt(log2e/TAU),
//     cast f16, MFMA-tiled layout: elem(r,k) ->
//     ((r>>4)*16 + (k>>3))*128 + (r&15)*8 + (k&7).  One wave per row.
//     ALSO: first 2048 waves build one-hot tiles in 16x16x16 B-frag layout.
__global__ void norm_kernel(const float* __restrict__ protos,
                            const float* __restrict__ proj2,
                            const float* __restrict__ proj3,
                            const int* __restrict__ t2, const int* __restrict__ t3,
                            _Float16* __restrict__ ftile,
                            _Float16* __restrict__ oh, int N, int M) {
    const float SCL = 3.8017368953f;  // sqrt(10 * log2(e))
    int w = threadIdx.x >> 6;
    int lane = threadIdx.x & 63;
    int g = lane >> 4, li = lane & 15;
    int row = blockIdx.x * (blockDim.x >> 6) + w;
    const int MT = M + 128;

    if (row < MT) {
        const float* src = nullptr;
        if (row < M)             src = (row < N) ? proj2 + (size_t)row * D
                                                 : proj3 + (size_t)(row - N) * D;
        else if (row < M + CCLS) src = protos + (size_t)(row - M) * D;
        float2 v = {0.f, 0.f};
        if (src) v = ((const float2*)src)[lane];
        float ss = wave_reduce_sum(v.x * v.x + v.y * v.y);
        float scale = src ? SCL / fmaxf(sqrtf(ss), 1e-12f) : 0.f;
        _Float16 h0 = (_Float16)(v.x * scale), h1 = (_Float16)(v.y * scale);
        int k0 = 2 * lane;
        size_t off = ((size_t)(row >> 4) * 16 + (k0 >> 3)) * 128 + (row & 15) * 8 + (k0 & 7);
        ftile[off] = h0; ftile[off + 1] = h1;
    }

    int wid = blockIdx.x * (blockDim.x >> 6) + w;
    if (wid < (M / 16) * 4) {
        int jt = wid >> 2, ct = wid & 3;
        int c = ct * 16 + li;
        f16x4 v;
        #pragma unroll
        for (int e = 0; e < 4; ++e) {
            int j = jt * 16 + 4 * g + e;
            int labj = (j < N) ? t2[j] : t3[j - N];
            v[e] = (labj == c) ? (_Float16)1.0f : (_Float16)0.0f;
        }
        *(f16x4*)(oh + ((size_t)(jt * 4 + ct)) * 256 + lane * 4) = v;
    }
}

// --- main: panel (64 rows) x chunk (32 slices) per block. 4 waves:
//     wave = (row-half ro, slice-half). Per wave: 32 rows, 16 slices.
//     Stage1: mfma_16x16x32_f16 (swapped) -> P tile (i=li, j=16n+4g+r).
//     exp2 -> cvt_pkrtz -> stage2 A-frag. Stage2: S[i][c] += P*onehot on
//     the MFMA pipe. ALL register arrays statically indexed (rule #20:
//     one runtime subscript demotes the array to scratch -> 120MB HBM
//     writes seen in R6). Diagonal mask = static index + cndmask.
__global__ __launch_bounds__(256, 2)
void sim_kernel(const _Float16* __restrict__ ftile,
                const _Float16* __restrict__ oh,
                float* __restrict__ Spart, float* __restrict__ E, int M) {
    __shared__ float Sl[64][SLP];

    const int panel = blockIdx.x;           // [0, M/64)
    const int chunk = blockIdx.y;           // [0, 4)
    const int t = threadIdx.x;
    const int w = t >> 6, lane = t & 63;
    const int g = lane >> 4, li = lane & 15;
    const int lo = g * 128 + li * 8;
    const int ro = (w & 1) * 32;            // row offset within panel
    const int half = w >> 1;                // slice half
    const int rtA = panel * 4 + (ro >> 4);
    const int ndBase = ro >> 4;             // 0 or 2

    // A fragments: this wave's 32 rows x 128 k (32 VGPRs)
    f16x8 a[2][4];
    #pragma unroll
    for (int m = 0; m < 2; ++m)
        #pragma unroll
        for (int kt = 0; kt < 4; ++kt)
            a[m][kt] = *(const f16x8*)(ftile + (size_t)(rtA + m) * 2048 + kt * 512 + lo);

    f32x4 acc2[2][4];                       // i = ro+16m+4g+r, c = 16nc+li
    #pragma unroll
    for (int m = 0; m < 2; ++m)
        #pragma unroll
        for (int nc = 0; nc < 4; ++nc)
            #pragma unroll
            for (int r = 0; r < 4; ++r) acc2[m][nc][r] = 0.f;

    const int sBase = chunk * 32 + half * 16;
    for (int si = 0; si < 16; ++si) {
        const int s = sBase + si;
        const int rb0 = s * 4;

        f32x4 acc1[2][4];
        #pragma unroll
        for (int m = 0; m < 2; ++m)
            #pragma unroll
            for (int n = 0; n < 4; ++n)
                #pragma unroll
                for (int r = 0; r < 4; ++r) acc1[m][n][r] = 0.f;

        #pragma unroll
        for (int kt = 0; kt < 4; ++kt) {
            f16x8 b[4];
            #pragma unroll
            for (int n = 0; n < 4; ++n)
                b[n] = *(const f16x8*)(ftile + (size_t)(rb0 + n) * 2048 + kt * 512 + lo);
            #pragma unroll
            for (int m = 0; m < 2; ++m)
                #pragma unroll
                for (int n = 0; n < 4; ++n)
                    acc1[m][n] = __builtin_amdgcn_mfma_f32_16x16x32_f16(b[n], a[m][kt], acc1[m][n], 0, 0, 0);
        }

        // diagonal mask: STATIC indices, runtime predicate (v_cndmask)
        if (s == panel) {
            #pragma unroll
            for (int m = 0; m < 2; ++m)
                #pragma unroll
                for (int n = 0; n < 4; ++n)
                    #pragma unroll
                    for (int r = 0; r < 4; ++r)
                        acc1[m][n][r] = (n == ndBase + m && 4 * g + r == li)
                                        ? -1e5f : acc1[m][n][r];
        }

        #pragma unroll
        for (int n = 0; n < 4; ++n) {
            f16x4 pa[2];
            #pragma unroll
            for (int m = 0; m < 2; ++m) {
                auto l2 = __builtin_amdgcn_cvt_pkrtz(exp2f(acc1[m][n][0]), exp2f(acc1[m][n][1]));
                auto h2 = __builtin_amdgcn_cvt_pkrtz(exp2f(acc1[m][n][2]), exp2f(acc1[m][n][3]));
                f16x4 p; p.x = l2.x; p.y = l2.y; p.z = h2.x; p.w = h2.y;
                pa[m] = p;
            }
            #pragma unroll
            for (int nc = 0; nc < 4; ++nc) {
                f16x4 ohf = *(const f16x4*)(oh + ((size_t)(s * 4 + n) * 4 + nc) * 256 + lane * 4);
                #pragma unroll
                for (int m = 0; m < 2; ++m)
                    acc2[m][nc] = __builtin_amdgcn_mfma_f32_16x16x16f16(pa[m], ohf, acc2[m][nc], 0, 0, 0);
            }
        }
    }

    // pair-reduce: half0 writes LDS; half1 adds and stores chunk partial
    if (half == 0) {
        #pragma unroll
        for (int m = 0; m < 2; ++m)
            #pragma unroll
            for (int nc = 0; nc < 4; ++nc)
                #pragma unroll
                for (int r = 0; r < 4; ++r)
                    Sl[ro + 16 * m + 4 * g + r][nc * 16 + li] = acc2[m][nc][r];
    }
    __syncthreads();
    if (half == 1) {
        float* dst = Spart + ((size_t)chunk * gridDim.x + panel) * 4096;
        #pragma unroll
        for (int m = 0; m < 2; ++m)
            #pragma unroll
            for (int nc = 0; nc < 4; ++nc)
                #pragma unroll
                for (int r = 0; r < 4; ++r) {
                    const int row = ro + 16 * m + 4 * g + r, c = nc * 16 + li;
                    dst[(size_t)row * 64 + c] = acc2[m][nc][r] + Sl[row][c];
                }
    }

    // proto slice: chunk 0, half 0 waves (both row halves), E[i][c] direct
    if (chunk == 0 && half == 0) {
        const int rbp = M >> 4;
        f32x4 accp[2][4];
        #pragma unroll
        for (int m = 0; m < 2; ++m)
            #pragma unroll
            for (int n = 0; n < 4; ++n)
                #pragma unroll
                for (int r = 0; r < 4; ++r) accp[m][n][r] = 0.f;
        #pragma unroll
        for (int kt = 0; kt < 4; ++kt) {
            f16x8 b[4];
            #pragma unroll
            for (int n = 0; n < 4; ++n)
                b[n] = *(const f16x8*)(ftile + (size_t)(rbp + n) * 2048 + kt * 512 + lo);
            #pragma unroll
            for (int m = 0; m < 2; ++m)
                #pragma unroll
                for (int n = 0; n < 4; ++n)
                    accp[m][n] = __builtin_amdgcn_mfma_f32_16x16x32_f16(b[n], a[m][kt], accp[m][n], 0, 0, 0);
        }
        #pragma unroll
        for (int m = 0; m < 2; ++m)
            #pragma unroll
            for (int n = 0; n < 4; ++n)
                #pragma unroll
                for (int r = 0; r < 4; ++r)
                    E[(size_t)(panel * 64 + ro + 16 * m + li) * 64 + n * 16 + 4 * g + r]
                        = exp2f(accp[m][n][r]);
    }
}

// --- per-row loss: one wave per row, lane = class ---------------------------
__global__ void fin_kernel(const int* __restrict__ t2, const int* __restrict__ t3,
                           const float* __restrict__ cls_freq,
                           const float* __restrict__ Spart, const float* __restrict__ E,
                           float* __restrict__ loss, int N, int M) {
    int w = threadIdx.x >> 6, lane = threadIdx.x & 63;
    int i = blockIdx.x * (blockDim.x >> 6) + w;
    if (i >= M) return;
    const int panel = i >> 6, lrow = i & 63;
    const size_t pbase = (size_t)panel * 4096 + (size_t)lrow * 64 + lane;
    const size_t cstride = (size_t)(M / 64) * 4096;
    float s = Spart[pbase] + Spart[pbase + cstride]
            + Spart[pbase + 2 * cstride] + Spart[pbase + 3 * cstride];
    float ev = E[(size_t)i * 64 + lane];
    float fr = cls_freq[lane];
    float sumS  = wave_reduce_sum(s);
    float sumEw = wave_reduce_sum(ev / fr);
    int lab = (i < N) ? t2[i] : t3[i - N];
    float nmr = __shfl(s + ev, lab, 64);
    float fl  = __shfl(fr, lab, 64);
    float denom = sumS / fl + sumEw;
    if (lane == 0) loss[i] = logf(denom + 1e-12f) - logf(nmr);
}

// --- mean reduction: one block -----------------------------------------------
__global__ void out_kernel(const float* __restrict__ loss, float* __restrict__ out, int M) {
    float s = 0.f;
    for (int i = threadIdx.x; i < M; i += 1024) s += loss[i];
    s = wave_reduce_sum(s);
    __shared__ float ws_[16];
    if ((threadIdx.x & 63) == 0) ws_[threadIdx.x >> 6] = s;
    __syncthreads();
    if (threadIdx.x == 0) {
        float t = 0.f;
        for (int k = 0; k < 16; ++k) t += ws_[k];
        out[0] = t / (float)M;
    }
}

extern "C" void kernel_launch(void* const* d_in, const int* in_sizes, int n_in,
                              void* d_out, int out_size, void* d_ws, size_t ws_size,
                              hipStream_t stream) {
    const float* protos = (const float*)d_in[0];
    const float* proj2  = (const float*)d_in[1];
    const int*   t2     = (const int*)d_in[2];
    const float* proj3  = (const float*)d_in[3];
    const int*   t3     = (const int*)d_in[4];
    float* out = (float*)d_out;

    const int N = in_sizes[1] / D;   // 4096
    const int M = 2 * N;             // 8192
    const int MT = M + 128;

    _Float16* ftile = (_Float16*)d_ws;                          // MT*D halfs
    _Float16* oh    = ftile + (size_t)MT * D;                   // (M/16)*4*256 halfs
    float* Spart    = (float*)(oh + (size_t)(M / 16) * 4 * 256); // 4*(M/64)*4096
    float* E        = Spart + (size_t)4 * (M / 64) * 4096;      // M*64
    float* loss     = E + (size_t)M * 64;                       // M
    float* cls_freq = loss + M;                                 // 64

    hist_kernel<<<1, 1024, 0, stream>>>(t2, t3, cls_freq, N, M);
    norm_kernel<<<(MT + 3) / 4, 256, 0, stream>>>(protos, proj2, proj3, t2, t3,
                                                  ftile, oh, N, M);
    dim3 grid(M / 64, 4);
    sim_kernel<<<grid, 256, 0, stream>>>(ftile, oh, Spart, E, M);
    fin_kernel<<<(M + 3) / 4, 256, 0, stream>>>(t2, t3, cls_freq, Spart, E, loss, N, M);
    out_kernel<<<1, 1024, 0, stream>>>(loss, out, M);
}